// Round 3
// baseline (186.156 us; speedup 1.0000x reference)
//
#include <hip/hip_runtime.h>

// TemporalSlotAttention: B=32, T=16, N=64, D=512
// out[b,t,n,d] = sum_j attn[b,n,j] * v_flat[b,j,t*D+d]
// attn = row-renorm(eps + softmax_over_i(Qf Kf^T * D^-0.5))

typedef short short8 __attribute__((ext_vector_type(8)));
typedef float f32x4  __attribute__((ext_vector_type(4)));

#define B_  32
#define T_  16
#define N_  64
#define D_  512
#define M_  32768           // B*T*N rows
#define TD_ 8192            // T*D
#define QKV_ONE 16777216    // B*N*TD elements per tensor (q/k/v)
#define BATCH_STRIDE 524288 // N*TD

static __device__ __forceinline__ float bf2f(short s) {
    unsigned int u = ((unsigned int)(unsigned short)s) << 16;
    float f; __builtin_memcpy(&f, &u, 4); return f;
}
static __device__ __forceinline__ short f2bf(float f) {
    unsigned int u; __builtin_memcpy(&u, &f, 4);
    unsigned int lsb = (u >> 16) & 1u;
    u += 0x7fffu + lsb;               // round-to-nearest-even
    return (short)(u >> 16);
}

// swizzle: XOR 16B-chunk index (bits 4-5) with row bits (bits 7-8).
// involution; spreads same-chunk column reads across banks (2-way = free).
static __device__ __forceinline__ unsigned swz(unsigned a) {
    return a ^ (((a >> 7) & 3u) << 4);
}

#define GLDS(gp, lp) __builtin_amdgcn_global_load_lds( \
    (const __attribute__((address_space(1))) unsigned int*)(gp), \
    (__attribute__((address_space(3))) unsigned int*)(lp), 16, 0, 0)

// ---------------- 1. LayerNorm -> bf16 norm [32768][512]  (+ fused W pack)
__global__ __launch_bounds__(256) void ln_pack_kernel(
    const float* __restrict__ x, const float* __restrict__ g,
    const float* __restrict__ bb, short* __restrict__ norm,
    const float* __restrict__ Wq, const float* __restrict__ Wk,
    const float* __restrict__ Wv, short* __restrict__ Wcat)
{
    if (blockIdx.x >= 8192) {      // W-pack tail: 3072 blocks x 256 = 786432
        int i = (blockIdx.x - 8192) * 256 + threadIdx.x;
        float v = (i < 262144) ? Wq[i] : (i < 524288) ? Wk[i - 262144] : Wv[i - 524288];
        Wcat[i] = f2bf(v);
        return;
    }
    int row = blockIdx.x * 4 + (threadIdx.x >> 6);
    int l = threadIdx.x & 63;
    const float4* xr = (const float4*)(x + (size_t)row * D_);
    float4 a = xr[l];
    float4 c = xr[l + 64];
    float s = a.x + a.y + a.z + a.w + c.x + c.y + c.z + c.w;
    #pragma unroll
    for (int m = 32; m; m >>= 1) s += __shfl_xor(s, m);
    float mu = s * (1.0f / 512.0f);
    float e0x = a.x - mu, e0y = a.y - mu, e0z = a.z - mu, e0w = a.w - mu;
    float e1x = c.x - mu, e1y = c.y - mu, e1z = c.z - mu, e1w = c.w - mu;
    float ss = e0x*e0x + e0y*e0y + e0z*e0z + e0w*e0w
             + e1x*e1x + e1y*e1y + e1z*e1z + e1w*e1w;
    #pragma unroll
    for (int m = 32; m; m >>= 1) ss += __shfl_xor(ss, m);
    float rstd = rsqrtf(ss * (1.0f / 512.0f) + 1e-5f);
    const float4* g4 = (const float4*)g;
    const float4* b4 = (const float4*)bb;
    float4 ga = g4[l], gc = g4[l + 64], ba = b4[l], bc = b4[l + 64];
    short* nr = norm + (size_t)row * D_;
    short4 o0 = make_short4(f2bf(e0x * rstd * ga.x + ba.x),
                            f2bf(e0y * rstd * ga.y + ba.y),
                            f2bf(e0z * rstd * ga.z + ba.z),
                            f2bf(e0w * rstd * ga.w + ba.w));
    short4 o1 = make_short4(f2bf(e1x * rstd * gc.x + bc.x),
                            f2bf(e1y * rstd * gc.y + bc.y),
                            f2bf(e1z * rstd * gc.z + bc.z),
                            f2bf(e1w * rstd * gc.w + bc.w));
    ((short4*)nr)[l] = o0;
    ((short4*)nr)[l + 64] = o1;
}

// ---------------- 3. QKV GEMM: C[32768][1536] = norm * Wcat^T + bias ----
// 128x128 tile, BK=32, 2-phase double-buffered global_load_lds pipeline
// (T3 minimum-2-phase: stage next BEFORE compute, one barrier per K-step),
// swizzled LDS (T2), XCD-chunked block swizzle (T1).
// writes bf16 into flat_slots layout: QKV[which][b][n][t*512 + o]
__global__ __launch_bounds__(256) void gemm_qkv(
    const short* __restrict__ A, const short* __restrict__ Bm,
    const float* __restrict__ bq, const float* __restrict__ bk,
    const float* __restrict__ bv, short* __restrict__ QKV)
{
    __shared__ short As[2][128 * 32];   // 2 x 8 KB, logical [row][32] bf16, swizzled
    __shared__ short Bs[2][128 * 32];
    int tid = threadIdx.x;
    // XCD-chunked swizzle: 3072 blocks = 8 XCDs x 384; within an XCD chunk,
    // n-tile (12) fastest so one 128KB A-panel + 1.5MB B live in its L2.
    int bid = blockIdx.x;
    int sb = (bid & 7) * 384 + (bid >> 3);
    int m_t = sb / 12, n_t = sb - m_t * 12;
    int m0 = m_t * 128;
    int n0 = n_t * 128;
    int w = tid >> 6, l = tid & 63;
    int wr = w >> 1, wc = w & 1;
    int lr = l & 15, hi = l >> 4;

    // staging: wave w, call c covers LDS bytes [c*4096 + w*1024 + l*16 ..+15]
    // LDS dest is linear (HW: base + lane*16); global source is pre-swizzled.
    unsigned y0 = ((unsigned)w << 10) + ((unsigned)l << 4);
    unsigned y1 = y0 + 4096;
    unsigned z0 = swz(y0), z1 = swz(y1);
    int r0 = z0 >> 6, c0 = (z0 >> 4) & 3;       // tile row, 8-elem chunk
    int r1 = z1 >> 6, c1 = (z1 >> 4) & 3;
    const short* Ag0 = A + (size_t)(m0 + r0) * 512 + c0 * 8;
    const short* Ag1 = A + (size_t)(m0 + r1) * 512 + c1 * 8;
    const short* Bg0 = Bm + (size_t)(n0 + r0) * 512 + c0 * 8;
    const short* Bg1 = Bm + (size_t)(n0 + r1) * 512 + c1 * 8;
    char* asb = (char*)As;
    char* bsb = (char*)Bs;

    // fragment read offsets (k-invariant), swizzled
    unsigned offA[4], offB[4];
    #pragma unroll
    for (int i = 0; i < 4; i++) {
        unsigned a = ((unsigned)(wr * 64 + i * 16 + lr) << 6) + ((unsigned)hi << 4);
        offA[i] = swz(a);
        unsigned b = ((unsigned)(wc * 64 + i * 16 + lr) << 6) + ((unsigned)hi << 4);
        offB[i] = swz(b);
    }

    f32x4 acc[4][4] = {};

#define STAGE(buf, k0_) do {                                   \
        char* da_ = asb + (buf) * 8192 + (w << 10);            \
        char* db_ = bsb + (buf) * 8192 + (w << 10);            \
        GLDS(Ag0 + (k0_), da_);                                \
        GLDS(Ag1 + (k0_), da_ + 4096);                         \
        GLDS(Bg0 + (k0_), db_);                                \
        GLDS(Bg1 + (k0_), db_ + 4096);                         \
    } while (0)

#define COMPUTE(buf) do {                                      \
        const char* ab_ = asb + (buf) * 8192;                  \
        const char* bb_ = bsb + (buf) * 8192;                  \
        short8 af[4], bfr[4];                                  \
        _Pragma("unroll")                                      \
        for (int mi = 0; mi < 4; mi++) af[mi] = *(short8*)(ab_ + offA[mi]); \
        _Pragma("unroll")                                      \
        for (int ni = 0; ni < 4; ni++) bfr[ni] = *(short8*)(bb_ + offB[ni]); \
        _Pragma("unroll")                                      \
        for (int mi = 0; mi < 4; mi++)                         \
            _Pragma("unroll")                                  \
            for (int ni = 0; ni < 4; ni++)                     \
                acc[mi][ni] = __builtin_amdgcn_mfma_f32_16x16x32_bf16( \
                    af[mi], bfr[ni], acc[mi][ni], 0, 0, 0);    \
    } while (0)

    STAGE(0, 0);
    __syncthreads();                      // prologue: buf0 visible
    #pragma unroll 1
    for (int tt = 0; tt < 7; ++tt) {
        STAGE(1, (tt * 2 + 1) * 32);      // issue next while computing current
        COMPUTE(0);
        __syncthreads();                  // drain (loads mostly landed) + barrier
        STAGE(0, (tt * 2 + 2) * 32);
        COMPUTE(1);
        __syncthreads();
    }
    STAGE(1, 480);
    COMPUTE(0);
    __syncthreads();
    COMPUTE(1);
#undef STAGE
#undef COMPUTE

    #pragma unroll
    for (int mi = 0; mi < 4; mi++) {
        #pragma unroll
        for (int ni = 0; ni < 4; ni++) {
            int gc = n0 + wc * 64 + ni * 16 + lr;
            int which = gc >> 9, o = gc & 511;
            const float* bias = (which == 0) ? bq : (which == 1) ? bk : bv;
            float bo = bias[o];
            #pragma unroll
            for (int r = 0; r < 4; r++) {
                int gr = m0 + wr * 64 + mi * 16 + hi * 4 + r;
                int b = gr >> 10, t = (gr >> 6) & 15, n = gr & 63;
                float v = acc[mi][ni][r] + bo;
                QKV[(size_t)which * QKV_ONE + (size_t)(b * 64 + n) * TD_ + t * 512 + o] = f2bf(v);
            }
        }
    }
}

// ---------------- 4. dots partial: Sp[b][kc][64][64] ----------------
// block = (b, kc); 4 waves each cover K=256 of the 1024-wide chunk
__global__ __launch_bounds__(256) void dots_partial(
    const short* __restrict__ QKV, float* __restrict__ Sp)
{
    int b = blockIdx.x >> 3;
    int kc = blockIdx.x & 7;
    int tid = threadIdx.x, w = tid >> 6, l = tid & 63;
    const short* Qb = QKV + (size_t)b * BATCH_STRIDE;
    const short* Kb = QKV + (size_t)QKV_ONE + (size_t)b * BATCH_STRIDE;
    int kbase = kc * 1024 + w * 256;
    f32x4 acc[4][4] = {};
    for (int ks = 0; ks < 256; ks += 32) {
        int k = kbase + ks + (l >> 4) * 8;
        short8 af[4], bfr[4];
        #pragma unroll
        for (int mi = 0; mi < 4; mi++)
            af[mi] = *(const short8*)&Qb[(size_t)(mi * 16 + (l & 15)) * TD_ + k];
        #pragma unroll
        for (int ni = 0; ni < 4; ni++)
            bfr[ni] = *(const short8*)&Kb[(size_t)(ni * 16 + (l & 15)) * TD_ + k];
        #pragma unroll
        for (int mi = 0; mi < 4; mi++)
            #pragma unroll
            for (int ni = 0; ni < 4; ni++)
                acc[mi][ni] = __builtin_amdgcn_mfma_f32_16x16x32_bf16(
                    af[mi], bfr[ni], acc[mi][ni], 0, 0, 0);
    }
    __shared__ float Sw[4][4096];
    #pragma unroll
    for (int mi = 0; mi < 4; mi++)
        #pragma unroll
        for (int ni = 0; ni < 4; ni++)
            #pragma unroll
            for (int r = 0; r < 4; r++)
                Sw[w][(mi * 16 + (l >> 4) * 4 + r) * 64 + ni * 16 + (l & 15)] = acc[mi][ni][r];
    __syncthreads();
    for (int c = tid; c < 4096; c += 256) {
        float s = Sw[0][c] + Sw[1][c] + Sw[2][c] + Sw[3][c];
        Sp[((size_t)b * 8 + kc) * 4096 + c] = s;
    }
}

// ---------------- 5. softmax over i, eps renorm over j ----------------
__global__ __launch_bounds__(256) void softmax_k(
    const float* __restrict__ Sp, float* __restrict__ attn)
{
    int b = blockIdx.x, tid = threadIdx.x;
    __shared__ float S[4096];
    for (int c = tid; c < 4096; c += 256) {
        float s = 0.0f;
        #pragma unroll
        for (int kc = 0; kc < 8; kc++) s += Sp[((size_t)b * 8 + kc) * 4096 + c];
        S[c] = s * 0.04419417382415922f;   // D^-0.5
    }
    __syncthreads();
    if (tid < 64) {             // column softmax (axis = i), column j = tid
        int j = tid;
        float m = -1e30f;
        for (int i = 0; i < 64; i++) m = fmaxf(m, S[i * 64 + j]);
        float s = 0.0f;
        for (int i = 0; i < 64; i++) {
            float e = __expf(S[i * 64 + j] - m);
            S[i * 64 + j] = e; s += e;
        }
        float inv = 1.0f / s;
        for (int i = 0; i < 64; i++) S[i * 64 + j] *= inv;
    }
    __syncthreads();
    if (tid < 64) {             // eps + renorm over j, row i = tid
        int i = tid;
        float rs = 0.0f;
        for (int j = 0; j < 64; j++) rs += S[i * 64 + j] + 1e-8f;
        float inv = 1.0f / rs;
        for (int j = 0; j < 64; j++)
            attn[(size_t)b * 4096 + i * 64 + j] = (S[i * 64 + j] + 1e-8f) * inv;
    }
}

// ---------------- 6. updates: out[b,t,i,d] = sum_j attn[i][j] * V[b,j,t*512+d]
__global__ __launch_bounds__(256) void updates_k(
    const short* __restrict__ QKV, const float* __restrict__ attn,
    float* __restrict__ out)
{
    int blk = blockIdx.x;               // 1024 = 32*16*2
    int b = blk >> 5, rem = blk & 31, t = rem >> 1, dc = rem & 1;
    int tid = threadIdx.x;
    int d = dc * 256 + tid;
    __shared__ float As2[4096];
    for (int c = tid; c < 4096; c += 256) As2[c] = attn[(size_t)b * 4096 + c];
    __syncthreads();
    const short* Vb = QKV + (size_t)2 * QKV_ONE + (size_t)b * BATCH_STRIDE;
    float acc[64];
    #pragma unroll
    for (int i = 0; i < 64; i++) acc[i] = 0.0f;
    for (int jb = 0; jb < 16; jb++) {
        float vj0 = bf2f(Vb[(size_t)(jb * 4 + 0) * TD_ + t * 512 + d]);
        float vj1 = bf2f(Vb[(size_t)(jb * 4 + 1) * TD_ + t * 512 + d]);
        float vj2 = bf2f(Vb[(size_t)(jb * 4 + 2) * TD_ + t * 512 + d]);
        float vj3 = bf2f(Vb[(size_t)(jb * 4 + 3) * TD_ + t * 512 + d]);
        #pragma unroll
        for (int i = 0; i < 64; i++) {
            float4 a = *(float4*)&As2[i * 64 + jb * 4];
            acc[i] = fmaf(a.x, vj0, acc[i]);
            acc[i] = fmaf(a.y, vj1, acc[i]);
            acc[i] = fmaf(a.z, vj2, acc[i]);
            acc[i] = fmaf(a.w, vj3, acc[i]);
        }
    }
    float* orow = out + (size_t)((b * 16 + t) * 64) * 512 + d;
    #pragma unroll
    for (int i = 0; i < 64; i++) orow[i * 512] = acc[i];
}

extern "C" void kernel_launch(void* const* d_in, const int* in_sizes, int n_in,
                              void* d_out, int out_size, void* d_ws, size_t ws_size,
                              hipStream_t stream) {
    (void)in_sizes; (void)n_in; (void)out_size; (void)ws_size;
    const float* x  = (const float*)d_in[0];
    const float* Wq = (const float*)d_in[1];
    const float* bq = (const float*)d_in[2];
    const float* Wk = (const float*)d_in[3];
    const float* bk = (const float*)d_in[4];
    const float* Wv = (const float*)d_in[5];
    const float* bv = (const float*)d_in[6];
    const float* lg = (const float*)d_in[7];
    const float* lb = (const float*)d_in[8];
    float* out = (float*)d_out;
    char* ws = (char*)d_ws;

    short* norm = (short*)ws;                      // 33,554,432 B
    short* Wcat = (short*)(ws + 33554432);         //  1,572,864 B
    short* QKV  = (short*)(ws + 35127296);         // 100,663,296 B (q|k|v flat bf16)
    float* Sp   = (float*)(ws + 135790592);        //  4,194,304 B
    float* attn = (float*)(ws + 139984896);        //    524,288 B  (total ~134 MiB)

    hipLaunchKernelGGL(ln_pack_kernel, dim3(11264), dim3(256), 0, stream,
                       x, lg, lb, norm, Wq, Wk, Wv, Wcat);
    hipLaunchKernelGGL(gemm_qkv,     dim3(3072),    dim3(256), 0, stream, norm, Wcat, bq, bk, bv, QKV);
    hipLaunchKernelGGL(dots_partial, dim3(256),     dim3(256), 0, stream, QKV, Sp);
    hipLaunchKernelGGL(softmax_k,    dim3(32),      dim3(256), 0, stream, Sp, attn);
    hipLaunchKernelGGL(updates_k,    dim3(1024),    dim3(256), 0, stream, QKV, attn, out);
}

// Round 4
// 139.569 us; speedup vs baseline: 1.3338x; 1.3338x over previous
//
#include <hip/hip_runtime.h>

// TemporalSlotAttention: B=32, T=16, N=64, D=512
// out[b,t,n,d] = sum_j attn[b,n,j] * v_flat[b,j,t*D+d]
// attn = row-renorm(eps + softmax_over_i(Qf Kf^T * D^-0.5))

typedef short short8 __attribute__((ext_vector_type(8)));
typedef float f32x4  __attribute__((ext_vector_type(4)));

#define B_  32
#define T_  16
#define N_  64
#define D_  512
#define TD_ 8192            // T*D
#define QKV_ONE 16777216    // B*N*TD elements per tensor (q/k/v)
#define BATCH_STRIDE 524288 // N*TD

static __device__ __forceinline__ float bf2f(short s) {
    unsigned int u = ((unsigned int)(unsigned short)s) << 16;
    float f; __builtin_memcpy(&f, &u, 4); return f;
}
static __device__ __forceinline__ short f2bf(float f) {
    unsigned int u; __builtin_memcpy(&u, &f, 4);
    unsigned int lsb = (u >> 16) & 1u;
    u += 0x7fffu + lsb;               // round-to-nearest-even
    return (short)(u >> 16);
}

// swizzle for 64B-row tiles (gemm): XOR 16B-chunk bits 4-5 with row bits 7-8.
static __device__ __forceinline__ unsigned swz(unsigned a) {
    return a ^ (((a >> 7) & 3u) << 4);
}

#define GLDS(gp, lp) __builtin_amdgcn_global_load_lds( \
    (const __attribute__((address_space(1))) unsigned int*)(gp), \
    (__attribute__((address_space(3))) unsigned int*)(lp), 16, 0, 0)

// ---------------- 1. LayerNorm -> bf16 norm [32768][512]  (+ fused W pack)
__global__ __launch_bounds__(256) void ln_pack_kernel(
    const float* __restrict__ x, const float* __restrict__ g,
    const float* __restrict__ bb, short* __restrict__ norm,
    const float* __restrict__ Wq, const float* __restrict__ Wk,
    const float* __restrict__ Wv, short* __restrict__ Wcat)
{
    if (blockIdx.x >= 8192) {      // W-pack tail: 3072 blocks x 256 = 786432
        int i = (blockIdx.x - 8192) * 256 + threadIdx.x;
        float v = (i < 262144) ? Wq[i] : (i < 524288) ? Wk[i - 262144] : Wv[i - 524288];
        Wcat[i] = f2bf(v);
        return;
    }
    int row = blockIdx.x * 4 + (threadIdx.x >> 6);
    int l = threadIdx.x & 63;
    const float4* xr = (const float4*)(x + (size_t)row * D_);
    float4 a = xr[l];
    float4 c = xr[l + 64];
    float s = a.x + a.y + a.z + a.w + c.x + c.y + c.z + c.w;
    #pragma unroll
    for (int m = 32; m; m >>= 1) s += __shfl_xor(s, m);
    float mu = s * (1.0f / 512.0f);
    float e0x = a.x - mu, e0y = a.y - mu, e0z = a.z - mu, e0w = a.w - mu;
    float e1x = c.x - mu, e1y = c.y - mu, e1z = c.z - mu, e1w = c.w - mu;
    float ss = e0x*e0x + e0y*e0y + e0z*e0z + e0w*e0w
             + e1x*e1x + e1y*e1y + e1z*e1z + e1w*e1w;
    #pragma unroll
    for (int m = 32; m; m >>= 1) ss += __shfl_xor(ss, m);
    float rstd = rsqrtf(ss * (1.0f / 512.0f) + 1e-5f);
    const float4* g4 = (const float4*)g;
    const float4* b4 = (const float4*)bb;
    float4 ga = g4[l], gc = g4[l + 64], ba = b4[l], bc = b4[l + 64];
    short* nr = norm + (size_t)row * D_;
    short4 o0 = make_short4(f2bf(e0x * rstd * ga.x + ba.x),
                            f2bf(e0y * rstd * ga.y + ba.y),
                            f2bf(e0z * rstd * ga.z + ba.z),
                            f2bf(e0w * rstd * ga.w + ba.w));
    short4 o1 = make_short4(f2bf(e1x * rstd * gc.x + bc.x),
                            f2bf(e1y * rstd * gc.y + bc.y),
                            f2bf(e1z * rstd * gc.z + bc.z),
                            f2bf(e1w * rstd * gc.w + bc.w));
    ((short4*)nr)[l] = o0;
    ((short4*)nr)[l + 64] = o1;
}

// ---------------- 3. QKV GEMM: C[32768][1536] = norm * Wcat^T + bias ----
// 128x128 tile, BK=32, single-buffer global_load_lds staging (round-2
// structure: measured faster than 2-phase dbuf which cost occupancy),
// swizzled LDS (T2, conflicts=0), XCD-chunked block swizzle (T1).
__global__ __launch_bounds__(256) void gemm_qkv(
    const short* __restrict__ A, const short* __restrict__ Bm,
    const float* __restrict__ bq, const float* __restrict__ bk,
    const float* __restrict__ bv, short* __restrict__ QKV)
{
    __shared__ short As[128 * 32];   // 8 KB, logical [row][32] bf16, swizzled
    __shared__ short Bs[128 * 32];
    int tid = threadIdx.x;
    // XCD-chunked swizzle: 3072 blocks = 8 XCDs x 384; n-tile fastest.
    int bid = blockIdx.x;
    int sb = (bid & 7) * 384 + (bid >> 3);
    int m_t = sb / 12, n_t = sb - m_t * 12;
    int m0 = m_t * 128;
    int n0 = n_t * 128;
    int w = tid >> 6, l = tid & 63;
    int wr = w >> 1, wc = w & 1;
    int lr = l & 15, hi = l >> 4;

    // staging: wave w, call c covers LDS bytes [c*4096 + w*1024 + l*16 ..+15]
    // LDS dest linear (HW: base + lane*16); global source pre-swizzled.
    unsigned y0 = ((unsigned)w << 10) + ((unsigned)l << 4);
    unsigned y1 = y0 + 4096;
    unsigned z0 = swz(y0), z1 = swz(y1);
    int r0 = z0 >> 6, c0 = (z0 >> 4) & 3;       // tile row, 8-elem chunk
    int r1 = z1 >> 6, c1 = (z1 >> 4) & 3;
    const short* Ag0 = A + (size_t)(m0 + r0) * 512 + c0 * 8;
    const short* Ag1 = A + (size_t)(m0 + r1) * 512 + c1 * 8;
    const short* Bg0 = Bm + (size_t)(n0 + r0) * 512 + c0 * 8;
    const short* Bg1 = Bm + (size_t)(n0 + r1) * 512 + c1 * 8;
    char* asb = (char*)As;
    char* bsb = (char*)Bs;
    char* ldsA0 = asb + (w << 10);
    char* ldsA1 = asb + 4096 + (w << 10);
    char* ldsB0 = bsb + (w << 10);
    char* ldsB1 = bsb + 4096 + (w << 10);

    // fragment read offsets (k-invariant), swizzled
    unsigned offA[4], offB[4];
    #pragma unroll
    for (int i = 0; i < 4; i++) {
        unsigned a = ((unsigned)(wr * 64 + i * 16 + lr) << 6) + ((unsigned)hi << 4);
        offA[i] = swz(a);
        unsigned b = ((unsigned)(wc * 64 + i * 16 + lr) << 6) + ((unsigned)hi << 4);
        offB[i] = swz(b);
    }

    f32x4 acc[4][4] = {};
    for (int k0 = 0; k0 < 512; k0 += 32) {
        __syncthreads();                       // prior reads done before overwrite
        GLDS(Ag0 + k0, ldsA0);
        GLDS(Ag1 + k0, ldsA1);
        GLDS(Bg0 + k0, ldsB0);
        GLDS(Bg1 + k0, ldsB1);
        __syncthreads();                       // compiler drains vmcnt before barrier
        short8 af[4], bfr[4];
        #pragma unroll
        for (int mi = 0; mi < 4; mi++) af[mi] = *(short8*)(asb + offA[mi]);
        #pragma unroll
        for (int ni = 0; ni < 4; ni++) bfr[ni] = *(short8*)(bsb + offB[ni]);
        #pragma unroll
        for (int mi = 0; mi < 4; mi++)
            #pragma unroll
            for (int ni = 0; ni < 4; ni++)
                acc[mi][ni] = __builtin_amdgcn_mfma_f32_16x16x32_bf16(
                    af[mi], bfr[ni], acc[mi][ni], 0, 0, 0);
    }

    #pragma unroll
    for (int mi = 0; mi < 4; mi++) {
        #pragma unroll
        for (int ni = 0; ni < 4; ni++) {
            int gc = n0 + wc * 64 + ni * 16 + lr;
            int which = gc >> 9, o = gc & 511;
            const float* bias = (which == 0) ? bq : (which == 1) ? bk : bv;
            float bo = bias[o];
            #pragma unroll
            for (int r = 0; r < 4; r++) {
                int gr = m0 + wr * 64 + mi * 16 + hi * 4 + r;
                int b = gr >> 10, t = (gr >> 6) & 15, n = gr & 63;
                float v = acc[mi][ni][r] + bo;
                QKV[(size_t)which * QKV_ONE + (size_t)(b * 64 + n) * TD_ + t * 512 + o] = f2bf(v);
            }
        }
    }
}

// ---------------- 4. dots partial: Sp[b][kc][64][64], kc = 16 chunks ----
// block = (b, kc); 4 waves each cover K=128 of the 512-wide chunk.
__global__ __launch_bounds__(256) void dots_partial(
    const short* __restrict__ QKV, float* __restrict__ Sp)
{
    int b = blockIdx.x >> 4;
    int kc = blockIdx.x & 15;
    int tid = threadIdx.x, w = tid >> 6, l = tid & 63;
    const short* Qb = QKV + (size_t)b * BATCH_STRIDE;
    const short* Kb = QKV + (size_t)QKV_ONE + (size_t)b * BATCH_STRIDE;
    int kbase = kc * 512 + w * 128;
    f32x4 acc[4][4] = {};
    #pragma unroll
    for (int ks = 0; ks < 128; ks += 32) {
        int k = kbase + ks + (l >> 4) * 8;
        short8 af[4], bfr[4];
        #pragma unroll
        for (int mi = 0; mi < 4; mi++)
            af[mi] = *(const short8*)&Qb[(size_t)(mi * 16 + (l & 15)) * TD_ + k];
        #pragma unroll
        for (int ni = 0; ni < 4; ni++)
            bfr[ni] = *(const short8*)&Kb[(size_t)(ni * 16 + (l & 15)) * TD_ + k];
        #pragma unroll
        for (int mi = 0; mi < 4; mi++)
            #pragma unroll
            for (int ni = 0; ni < 4; ni++)
                acc[mi][ni] = __builtin_amdgcn_mfma_f32_16x16x32_bf16(
                    af[mi], bfr[ni], acc[mi][ni], 0, 0, 0);
    }
    __shared__ float Sw[4][4096];
    #pragma unroll
    for (int mi = 0; mi < 4; mi++)
        #pragma unroll
        for (int ni = 0; ni < 4; ni++)
            #pragma unroll
            for (int r = 0; r < 4; r++)
                Sw[w][(mi * 16 + (l >> 4) * 4 + r) * 64 + ni * 16 + (l & 15)] = acc[mi][ni][r];
    __syncthreads();
    for (int c = tid; c < 4096; c += 256) {
        float s = Sw[0][c] + Sw[1][c] + Sw[2][c] + Sw[3][c];
        Sp[((size_t)b * 16 + kc) * 4096 + c] = s;
    }
}

// ---------------- 5. softmax over i, eps renorm over j (all 256 thr) ----
__global__ __launch_bounds__(256) void softmax_k(
    const float* __restrict__ Sp, float* __restrict__ attn)
{
    int b = blockIdx.x, tid = threadIdx.x;
    __shared__ float S[64][65];              // +1 pad: row-phase conflicts
    __shared__ float Pm[4][64], Pe[4][64], Pr[4][64];
    for (int c = tid; c < 4096; c += 256) {
        float s = 0.0f;
        #pragma unroll
        for (int kc = 0; kc < 16; kc++) s += Sp[((size_t)b * 16 + kc) * 4096 + c];
        S[c >> 6][c & 63] = s * 0.04419417382415922f;   // D^-0.5
    }
    __syncthreads();
    int q = tid >> 6, j = tid & 63;
    float m = -1e30f;
    #pragma unroll
    for (int ii = 0; ii < 16; ii++) m = fmaxf(m, S[q * 16 + ii][j]);
    Pm[q][j] = m;
    __syncthreads();
    m = fmaxf(fmaxf(Pm[0][j], Pm[1][j]), fmaxf(Pm[2][j], Pm[3][j]));
    float s = 0.0f;
    #pragma unroll
    for (int ii = 0; ii < 16; ii++) {
        float e = __expf(S[q * 16 + ii][j] - m);
        S[q * 16 + ii][j] = e; s += e;
    }
    Pe[q][j] = s;
    __syncthreads();
    float inv = 1.0f / (Pe[0][j] + Pe[1][j] + Pe[2][j] + Pe[3][j]);
    #pragma unroll
    for (int ii = 0; ii < 16; ii++) S[q * 16 + ii][j] *= inv;
    __syncthreads();
    // phase B: lanes index rows i, sum over j quarter
    int i = j;
    float rs = 0.0f;
    #pragma unroll
    for (int jj = 0; jj < 16; jj++) rs += S[i][q * 16 + jj] + 1e-8f;
    Pr[q][i] = rs;
    __syncthreads();
    float inv2 = 1.0f / (Pr[0][i] + Pr[1][i] + Pr[2][i] + Pr[3][i]);
    #pragma unroll
    for (int jj = 0; jj < 16; jj++)
        attn[(size_t)b * 4096 + i * 64 + q * 16 + jj] =
            (S[i][q * 16 + jj] + 1e-8f) * inv2;
}

// ---------------- 6. updates (MFMA): out[b,t,i,d] = sum_j attn[i][j]*V[j][t*512+d]
// block = (b,t) of 512; attn (bf16) + V^T staged in LDS (XOR-swizzled rows),
// wave w computes the d-chunk [w*128, w*128+128) as 4x8 16x16x32 MFMA tiles.
__global__ __launch_bounds__(256, 2) void updates_k(
    const short* __restrict__ QKV, const float* __restrict__ attn,
    float* __restrict__ out)
{
    int blk = blockIdx.x;               // 512 = 32 b * 16 t
    int b = blk >> 4, t = blk & 15;
    int tid = threadIdx.x, w = tid >> 6, l = tid & 63;
    int lr = l & 15, hi = l >> 4;
    __shared__ short VT[512 * 64];      // [d][j] bf16, 128B rows, swizzled
    __shared__ short AT[64 * 64];       // [i][j] bf16, 128B rows, swizzled
    const short* Vb = QKV + (size_t)2 * QKV_ONE + (size_t)b * BATCH_STRIDE + t * 512;

    // stage attn -> bf16 LDS: each wave-instr covers one full row i
    #pragma unroll
    for (int r = 0; r < 16; r++) {
        int idx = r * 256 + tid;        // i = idx>>6, j = idx&63
        int i = idx >> 6, jj = idx & 63;
        float v = attn[(size_t)b * 4096 + idx];
        unsigned off = ((unsigned)(i * 128 + jj * 2)) ^ (((unsigned)(i & 7)) << 4);
        *(short*)((char*)AT + off) = f2bf(v);
    }
    // stage V^T: thread owns row j = tid&63; global reads scattered (L3-hot),
    // LDS writes conflict-free (lanes span j at fixed d)
    int j = tid & 63, dg = tid >> 6;
    #pragma unroll
    for (int ii = 0; ii < 16; ii++) {
        int d0 = dg * 128 + ii * 8;
        short8 v = *(const short8*)&Vb[(size_t)j * TD_ + d0];
        #pragma unroll
        for (int e = 0; e < 8; e++) {
            int d = d0 + e;
            unsigned off = ((unsigned)(d * 128 + j * 2)) ^ (((unsigned)(d & 7)) << 4);
            *(short*)((char*)VT + off) = v[e];
        }
    }
    __syncthreads();

    f32x4 acc[4][8] = {};
    #pragma unroll
    for (int ks = 0; ks < 2; ks++) {
        short8 af[4], bfr[8];
        #pragma unroll
        for (int mi = 0; mi < 4; mi++) {
            int i = mi * 16 + lr;
            unsigned off = ((unsigned)(i * 128 + ks * 64 + hi * 16)) ^ (((unsigned)(i & 7)) << 4);
            af[mi] = *(short8*)((char*)AT + off);
        }
        #pragma unroll
        for (int ni = 0; ni < 8; ni++) {
            int dr = w * 128 + ni * 16 + lr;
            unsigned off = ((unsigned)(dr * 128 + ks * 64 + hi * 16)) ^ (((unsigned)(dr & 7)) << 4);
            bfr[ni] = *(short8*)((char*)VT + off);
        }
        #pragma unroll
        for (int mi = 0; mi < 4; mi++)
            #pragma unroll
            for (int ni = 0; ni < 8; ni++)
                acc[mi][ni] = __builtin_amdgcn_mfma_f32_16x16x32_bf16(
                    af[mi], bfr[ni], acc[mi][ni], 0, 0, 0);
    }

    float* ob = out + (size_t)((b * 16 + t) * 64) * 512;
    #pragma unroll
    for (int mi = 0; mi < 4; mi++)
        #pragma unroll
        for (int ni = 0; ni < 8; ni++) {
            int d = w * 128 + ni * 16 + lr;
            #pragma unroll
            for (int r = 0; r < 4; r++) {
                int i = mi * 16 + hi * 4 + r;
                ob[(size_t)i * 512 + d] = acc[mi][ni][r];
            }
        }
}

extern "C" void kernel_launch(void* const* d_in, const int* in_sizes, int n_in,
                              void* d_out, int out_size, void* d_ws, size_t ws_size,
                              hipStream_t stream) {
    (void)in_sizes; (void)n_in; (void)out_size; (void)ws_size;
    const float* x  = (const float*)d_in[0];
    const float* Wq = (const float*)d_in[1];
    const float* bq = (const float*)d_in[2];
    const float* Wk = (const float*)d_in[3];
    const float* bk = (const float*)d_in[4];
    const float* Wv = (const float*)d_in[5];
    const float* bv = (const float*)d_in[6];
    const float* lg = (const float*)d_in[7];
    const float* lb = (const float*)d_in[8];
    float* out = (float*)d_out;
    char* ws = (char*)d_ws;

    short* norm = (short*)ws;                      // 33,554,432 B (dead after gemm)
    short* Wcat = (short*)(ws + 33554432);         //  1,572,864 B
    short* QKV  = (short*)(ws + 35127296);         // 100,663,296 B (q|k|v flat bf16)
    float* Sp   = (float*)ws;                      //  8,388,608 B (aliases norm)
    float* attn = (float*)(ws + 8388608);          //    524,288 B (aliases norm)

    hipLaunchKernelGGL(ln_pack_kernel, dim3(11264), dim3(256), 0, stream,
                       x, lg, lb, norm, Wq, Wk, Wv, Wcat);
    hipLaunchKernelGGL(gemm_qkv,     dim3(3072),    dim3(256), 0, stream, norm, Wcat, bq, bk, bv, QKV);
    hipLaunchKernelGGL(dots_partial, dim3(512),     dim3(256), 0, stream, QKV, Sp);
    hipLaunchKernelGGL(softmax_k,    dim3(32),      dim3(256), 0, stream, Sp, attn);
    hipLaunchKernelGGL(updates_k,    dim3(512),     dim3(256), 0, stream, QKV, attn, out);
}